// Round 1
// 98.607 us; speedup vs baseline: 1.0266x; 1.0266x over previous
//
#include <hip/hip_runtime.h>
#include <math.h>

#define BB 4
#define CI 64
#define CO 64
#define HH 96
#define WW 96
#define HW (HH*WW)      // 9216
#define K2 9
#define PADC 1

// fused tiling: 8x4-px tiles
#define TW 8
#define TH 4
#define TPXT (TW*TH)        // 32 px per tile
#define TBX (WW/TW)         // 12
#define TBY (HH/TH)         // 24
#define NTILB (TBX*TBY)     // 288 tiles per batch
#define NTILES (BB*NTILB)   // 1152

// LDS window: rows [h0-4, h0+TH+8], cols [w0-4, w0+15]
#define WR (TH+9)           // 13 rows
#define WC 20               // 20 cols (5 float4 chunks)
#define SREC 72             // ushorts per px record (144B: 128B data + 16B pad -> 2-way banks)
#define NSLOT (WR*WC)       // 260 slots

typedef __attribute__((ext_vector_type(8))) short short8;
typedef __attribute__((ext_vector_type(4))) float float4v;
typedef __attribute__((ext_vector_type(2))) float float2v;
typedef __attribute__((ext_vector_type(4))) unsigned int uint4v;
typedef __attribute__((ext_vector_type(4))) int int4v;

// ws layout: Wf (18*64*32 ushort) + MWf (18*16*32 ushort)
#define WF_USHORTS (18*64*32)
#define MWF_USHORTS (18*16*32)

__device__ __forceinline__ float bf2f(short s) {
    return __uint_as_float(((unsigned int)(unsigned short)s) << 16);
}
__device__ __forceinline__ short f2bf(float f) {
    unsigned int u = __float_as_uint(f);
    u = (u + 0x7fffu + ((u >> 16) & 1u)) >> 16;   // RNE
    return (short)u;
}
// HW packed fp32->bf16x2, RNE (identical result to f2bf pair) [T12 recipe]
__device__ __forceinline__ unsigned int cvt_pk_bf16(float lo, float hi) {
    unsigned int r;
    asm("v_cvt_pk_bf16_f32 %0, %1, %2" : "=v"(r) : "v"(lo), "v"(hi));
    return r;
}
// unpack bf16x2 word -> two f32 (lo, hi) as float2
__device__ __forceinline__ float2v bfpair(unsigned int u) {
    float2v r;
    r.x = __uint_as_float(u << 16);
    r.y = __uint_as_float(u & 0xffff0000u);
    return r;
}

// XCD swizzle: XCD g serves only batch g&3 so its 4MB L2 caches that batch's
// x slice (2.36MB fp32). [R3: FETCH 15->4MB verified with same scheme]
__device__ __forceinline__ void unswz(int bid, int* b, int* ty, int* tx) {
    int g = bid & 7, r = bid >> 3;      // r in [0,144)
    *b = g & 3;
    int tile = (g >> 2) * 144 + r;      // [0,288)
    *ty = tile / TBX; *tx = tile % TBX;
}

// ---------------- prep: weight pack only (xT eliminated) ----------------
__global__ __launch_bounds__(256) void pack_kernel(const float* __restrict__ wgt,
                                                   const float* __restrict__ mw,
                                                   unsigned short* __restrict__ Wf,
                                                   unsigned short* __restrict__ MWf) {
    int i = blockIdx.x * 256 + threadIdx.x;
    if (i < WF_USHORTS) {
        int frag = i >> 11;
        int o = (i >> 5) & 63;
        int tt = i & 31;
        int k = frag >> 1, cc = frag & 1;
        int c = cc * 32 + tt;
        Wf[i] = (unsigned short)f2bf(wgt[o * 576 + c * 9 + k]);
    } else if (i < WF_USHORTS + MWF_USHORTS) {
        int e = i - WF_USHORTS;
        int frag = e >> 9;
        int m = (e >> 5) & 15;
        int tt = e & 31;
        int q = frag >> 1, cc = frag & 1;
        int c = cc * 32 + tt;
        MWf[e] = (m < 9) ? (unsigned short)f2bf(mw[m * 576 + c * 9 + q]) : 0;
    }
}

// ---------------- fused: LDS-window staged mask conv + deform + GEMM ----------
// Block = 4 waves over one 8x4 tile: wave (pg = wv>>1: px-group of 16,
// ch = wv&1: 32-channel half). Gathers hit the LDS window; rare out-of-window
// corners (|offset| > ~3) fall back to exec-masked global reads of x.
// R(this): per-corner addr math hoisted to phase B (tags), meta as [k][px][4]
// b128 records (2-way banks = free), blend in packed f32 + v_cvt_pk_bf16_f32,
// wave-uniform fallback test (__any) so the 4 corner ds_read_b128 are
// unconditional in the common path.
__global__ __launch_bounds__(256, 3) void fused_kernel(const float* __restrict__ x,
                                                       const float* __restrict__ off,
                                                       const float* __restrict__ mbias,
                                                       const unsigned short* __restrict__ Wf,
                                                       const unsigned short* __restrict__ MWf,
                                                       float* __restrict__ out) {
    __shared__ __align__(16) unsigned short win[NSLOT * SREC];   // 37,440 B
    __shared__ float s_mred[2][K2][TPXT];                        // 2,304 B
    __shared__ __align__(16) int   s_tag[K2][TPXT][4];           // 4,608 B
    __shared__ __align__(16) float s_wt[K2][TPXT][4];            // 4,608 B
    float* part = (float*)win;   // [2][16][64] aliased AFTER window is dead

    int t = threadIdx.x;
    int lane = t & 63, wv = t >> 6;
    int pg = wv >> 1, ch = wv & 1;
    int n = lane & 15, quad = lane >> 4;
    int b, ty, tx; unswz(blockIdx.x, &b, &ty, &tx);
    int h0 = ty * TH, w0 = tx * TW;
    int wr0 = h0 - 4, wc0 = w0 - 4;
    const float* xb = x + (size_t)b * CI * HW;

    // ---- stage window: fp32 x -> bf16 LDS records, transposed on the fly ----
    // task e = (r, chp, c4): row r, channel-pair 2chp, col-chunk of 4
    for (int e = t; e < WR * 32 * 5; e += 256) {
        int r = e / 160, rem = e % 160, chp = rem / 5, c4 = rem % 5;
        int row = min(max(wr0 + r, 0), HH - 1);
        int c0c = wc0 + c4 * 4;
        const float* s0 = xb + (size_t)(2 * chp) * HW + row * WW;
        const float* s1 = s0 + HW;
        float v0[4], v1[4];
        if (c0c >= 0 && c0c + 3 < WW) {
            float4v a = *(const float4v*)(s0 + c0c);
            float4v bq = *(const float4v*)(s1 + c0c);
            v0[0]=a[0]; v0[1]=a[1]; v0[2]=a[2]; v0[3]=a[3];
            v1[0]=bq[0]; v1[1]=bq[1]; v1[2]=bq[2]; v1[3]=bq[3];
        } else {
            #pragma unroll
            for (int j = 0; j < 4; j++) {
                int cc2 = min(max(c0c + j, 0), WW - 1);
                v0[j] = s0[cc2]; v1[j] = s1[cc2];
            }
        }
        #pragma unroll
        for (int j = 0; j < 4; j++) {
            *(unsigned int*)&win[(r * WC + c4 * 4 + j) * SREC + 2 * chp] =
                cvt_pk_bf16(v0[j], v1[j]);
        }
    }
    __syncthreads();

    int pxl = pg * 16 + n;                 // px within tile
    int ly = pxl >> 3, lx = pxl & 7;
    int h = h0 + ly, wcc = w0 + lx;
    int cbase_us = ch * 32 + quad * 8;     // ushort offset within record

    // ---- phase A: mask-conv partials via MFMA, B-frags from LDS window ----
    {
        float4v macc = {0.f, 0.f, 0.f, 0.f};
        #pragma unroll
        for (int q = 0; q < 9; q++) {
            int hh = h + q / 3 - 1, ww2 = wcc + q % 3 - 1;
            bool valid = (hh >= 0) && (hh < HH) && (ww2 >= 0) && (ww2 < WW);
            short8 bfrag = {0, 0, 0, 0, 0, 0, 0, 0};
            if (valid) {
                int slot = (hh - wr0) * WC + (ww2 - wc0);   // always in window
                bfrag = *(const short8*)&win[slot * SREC + cbase_us];
            }
            short8 afrag = *(const short8*)(MWf + ((size_t)((q * 2 + ch) * 16 + n)) * 32 + quad * 8);
            macc = __builtin_amdgcn_mfma_f32_16x16x32_bf16(afrag, bfrag, macc, 0, 0, 0);
        }
        #pragma unroll
        for (int r = 0; r < 4; r++) {
            int row = quad * 4 + r;
            if (row < 9) s_mred[ch][row][pxl] = macc[r];
        }
    }
    __syncthreads();

    // ---- phase B: sampling metadata (corner tags precomputed, mask folded) ----
    // tag >= 0 : byte offset of window record (slot * 144)
    // tag <  0 : 0x80000000 | (y*WW + x) global-pixel fallback
    for (int e = t; e < K2 * TPXT; e += 256) {
        int k = e >> 5, pe = e & 31;
        int ph = h0 + (pe >> 3), pw = w0 + (pe & 7);
        int p = ph * WW + pw;
        float oy = off[((size_t)b * 2 * K2 + 2 * k) * HW + p];
        float ox = off[((size_t)b * 2 * K2 + 2 * k + 1) * HW + p];
        float s = s_mred[0][k][pe] + s_mred[1][k][pe] + mbias[k];
        float m = 1.f / (1.f + expf(-s));
        float py  = (float)(ph - PADC + k / 3) + oy;
        float pxf = (float)(pw - PADC + k % 3) + ox;
        float y0f = floorf(py), x0f = floorf(pxf);
        float wy = py - y0f, wx = pxf - x0f;
        int y0 = (int)y0f, x0 = (int)x0f;
        int y1 = y0 + 1, x1 = x0 + 1;
        int y0c = min(max(y0, 0), HH - 1), y1c = min(max(y1, 0), HH - 1);
        int x0c = min(max(x0, 0), WW - 1), x1c = min(max(x1, 0), WW - 1);
        bool vy0 = (y0 >= 0) && (y0 < HH), vy1 = (y1 >= 0) && (y1 < HH);
        bool vx0 = (x0 >= 0) && (x0 < WW), vx1 = (x1 >= 0) && (x1 < WW);
        float w00 = (1.f - wy) * (1.f - wx) * m; if (!(vy0 && vx0)) w00 = 0.f;
        float w01 = (1.f - wy) * wx * m;         if (!(vy0 && vx1)) w01 = 0.f;
        float w10 = wy * (1.f - wx) * m;         if (!(vy1 && vx0)) w10 = 0.f;
        float w11 = wy * wx * m;                 if (!(vy1 && vx1)) w11 = 0.f;
        int rA = y0c - wr0, rB = y1c - wr0;
        int cA = x0c - wc0, cB = x1c - wc0;
        bool irA = (unsigned)rA < (unsigned)WR, irB = (unsigned)rB < (unsigned)WR;
        bool jcA = (unsigned)cA < (unsigned)WC, jcB = (unsigned)cB < (unsigned)WC;
        int gy0 = y0c * WW, gy1 = y1c * WW;
        s_tag[k][pe][0] = (irA && jcA) ? (rA * WC + cA) * (SREC * 2)
                                       : (int)(0x80000000u | (unsigned)(gy0 + x0c));
        s_tag[k][pe][1] = (irA && jcB) ? (rA * WC + cB) * (SREC * 2)
                                       : (int)(0x80000000u | (unsigned)(gy0 + x1c));
        s_tag[k][pe][2] = (irB && jcA) ? (rB * WC + cA) * (SREC * 2)
                                       : (int)(0x80000000u | (unsigned)(gy1 + x0c));
        s_tag[k][pe][3] = (irB && jcB) ? (rB * WC + cB) * (SREC * 2)
                                       : (int)(0x80000000u | (unsigned)(gy1 + x1c));
        s_wt[k][pe][0] = w00; s_wt[k][pe][1] = w01;
        s_wt[k][pe][2] = w10; s_wt[k][pe][3] = w11;
    }
    __syncthreads();

    // ---- phase C: gather from LDS window (global fallback) + blend + MFMA ----
    float4v acc0 = {0.f, 0.f, 0.f, 0.f};
    float4v acc1 = {0.f, 0.f, 0.f, 0.f};
    float4v acc2 = {0.f, 0.f, 0.f, 0.f};
    float4v acc3 = {0.f, 0.f, 0.f, 0.f};
    const float* xfb = xb + (size_t)(ch * 32 + quad * 8) * HW;   // fallback channel base
    const char* wbase = (const char*)win + (size_t)(cbase_us * 2);

    #pragma unroll
    for (int k = 0; k < 9; k++) {
        int4v tg = *(const int4v*)&s_tag[k][pxl][0];
        float4v wt = *(const float4v*)&s_wt[k][pxl][0];
        uint4v Cg[4];
        if (!__any((tg[0] | tg[1] | tg[2] | tg[3]) < 0)) {
            // common path: all 4 corners in-window, unconditional b128 reads
            #pragma unroll
            for (int cor = 0; cor < 4; cor++)
                Cg[cor] = *(const uint4v*)(wbase + tg[cor]);
        } else {
            #pragma unroll
            for (int cor = 0; cor < 4; cor++) {
                int tag = tg[cor];
                uint4v u;
                if (tag >= 0) {
                    u = *(const uint4v*)(wbase + tag);
                } else {
                    const float* fs = xfb + (tag & 0x7fffffff);
                    #pragma unroll
                    for (int p2 = 0; p2 < 4; p2++) {
                        u[p2] = (unsigned int)(unsigned short)f2bf(fs[(size_t)(2 * p2) * HW]) |
                                ((unsigned int)(unsigned short)f2bf(fs[(size_t)(2 * p2 + 1) * HW]) << 16);
                    }
                }
                Cg[cor] = u;
            }
        }
        float2v w0v = {wt[0], wt[0]}, w1v = {wt[1], wt[1]};
        float2v w2v = {wt[2], wt[2]}, w3v = {wt[3], wt[3]};
        uint4v bfw;
        #pragma unroll
        for (int p2 = 0; p2 < 4; p2++) {
            float2v v = bfpair(Cg[0][p2]) * w0v;
            v += bfpair(Cg[1][p2]) * w1v;
            v += bfpair(Cg[2][p2]) * w2v;
            v += bfpair(Cg[3][p2]) * w3v;
            bfw[p2] = cvt_pk_bf16(v.x, v.y);
        }
        union { uint4v u; short8 s; } cv; cv.u = bfw;
        short8 bfrag = cv.s;
        const unsigned short* wp = Wf + (size_t)((k * 2 + ch) * 64) * 32 + quad * 8;
        short8 a0 = *(const short8*)(wp + (0 * 16 + n) * 32);
        short8 a1 = *(const short8*)(wp + (1 * 16 + n) * 32);
        short8 a2 = *(const short8*)(wp + (2 * 16 + n) * 32);
        short8 a3 = *(const short8*)(wp + (3 * 16 + n) * 32);
        acc0 = __builtin_amdgcn_mfma_f32_16x16x32_bf16(a0, bfrag, acc0, 0, 0, 0);
        acc1 = __builtin_amdgcn_mfma_f32_16x16x32_bf16(a1, bfrag, acc1, 0, 0, 0);
        acc2 = __builtin_amdgcn_mfma_f32_16x16x32_bf16(a2, bfrag, acc2, 0, 0, 0);
        acc3 = __builtin_amdgcn_mfma_f32_16x16x32_bf16(a3, bfrag, acc3, 0, 0, 0);
    }

    // ---- cross-wave ch-reduce via part (aliases dead window) + epilogue ----
    __syncthreads();   // all window reads complete before alias write
    if (ch == 1) {
        #pragma unroll
        for (int r = 0; r < 4; r++) {
            part[(pg * 16 + 0 * 4 + r) * 64 + lane] = acc0[r];
            part[(pg * 16 + 1 * 4 + r) * 64 + lane] = acc1[r];
            part[(pg * 16 + 2 * 4 + r) * 64 + lane] = acc2[r];
            part[(pg * 16 + 3 * 4 + r) * 64 + lane] = acc3[r];
        }
    }
    __syncthreads();
    if (ch == 0) {
        float* ob = out + (size_t)b * CO * HW + h * WW + wcc;
        #pragma unroll
        for (int r = 0; r < 4; r++) {
            ob[(size_t)(0 * 16 + quad * 4 + r) * HW] =
                acc0[r] + part[(pg * 16 + 0 * 4 + r) * 64 + lane];
            ob[(size_t)(1 * 16 + quad * 4 + r) * HW] =
                acc1[r] + part[(pg * 16 + 1 * 4 + r) * 64 + lane];
            ob[(size_t)(2 * 16 + quad * 4 + r) * HW] =
                acc2[r] + part[(pg * 16 + 2 * 4 + r) * 64 + lane];
            ob[(size_t)(3 * 16 + quad * 4 + r) * HW] =
                acc3[r] + part[(pg * 16 + 3 * 4 + r) * 64 + lane];
        }
    }
}

extern "C" void kernel_launch(void* const* d_in, const int* in_sizes, int n_in,
                              void* d_out, int out_size, void* d_ws, size_t ws_size,
                              hipStream_t stream) {
    const float* x   = (const float*)d_in[0];
    const float* off = (const float*)d_in[1];
    const float* wgt = (const float*)d_in[2];
    const float* mw  = (const float*)d_in[3];
    const float* mb  = (const float*)d_in[4];
    float* out = (float*)d_out;

    unsigned short* Wf  = (unsigned short*)d_ws;
    unsigned short* MWf = Wf + WF_USHORTS;

    hipLaunchKernelGGL(pack_kernel, dim3((WF_USHORTS + MWF_USHORTS + 255) / 256), dim3(256),
                       0, stream, wgt, mw, Wf, MWf);
    hipLaunchKernelGGL(fused_kernel, dim3(NTILES), dim3(256), 0, stream,
                       x, off, mb, Wf, MWf, out);
}